// Round 3
// baseline (1035.165 us; speedup 1.0000x reference)
//
#include <hip/hip_runtime.h>

#define NB 8
#define NN 50000
#define NC 64
#define NE 400000

// ---- CSR build --------------------------------------------------------------
__global__ void cheb_count(const int* __restrict__ ei, int* __restrict__ cnt) {
  int e = blockIdx.x * blockDim.x + threadIdx.x;
  if (e >= NE) return;
  int r = ei[e], c = ei[NE + e];
  if (r != c) atomicAdd(&cnt[r], 1);
}

__global__ void cheb_offsets(const int* __restrict__ cnt, float* __restrict__ dinv,
                             int* __restrict__ rowptr, int* __restrict__ cur,
                             int* __restrict__ total) {
  int n = blockIdx.x * blockDim.x + threadIdx.x;
  if (n >= NN) return;
  int c = cnt[n];
  dinv[n] = (c > 0) ? rsqrtf((float)c) : 0.0f;
  int s = atomicAdd(total, c);   // bucket order irrelevant for a sum: no scan needed
  rowptr[n] = s;
  cur[n] = s;
}

__global__ void cheb_scatter(const int* __restrict__ ei, const float* __restrict__ dinv,
                             int* __restrict__ cur, int2* __restrict__ edges) {
  int e = blockIdx.x * blockDim.x + threadIdx.x;
  if (e >= NE) return;
  int r = ei[e], c = ei[NE + e];
  if (r == c) return;
  int pos = atomicAdd(&cur[r], 1);
  float lap = -dinv[r] * dinv[c];
  edges[pos] = make_int2(c, __float_as_int(lap));
}

// ---- Wc = [W0 - W2; W1; 2*W2] ----------------------------------------------
__global__ void cheb_wc(const float* __restrict__ w, float* __restrict__ wc) {
  int i = blockIdx.x * blockDim.x + threadIdx.x;
  if (i >= NC * NC) return;
  float w0 = w[i];
  float w1 = w[NC * NC + i];
  float w2 = w[2 * NC * NC + i];
  wc[i] = w0 - w2;
  wc[NC * NC + i] = w1;
  wc[2 * NC * NC + i] = 2.0f * w2;
}

// ---- prop: y[b,n,:] = sum_j lap[j] * t[b,col[j],:]; one wave per (b,n) -----
__global__ __launch_bounds__(256) void cheb_prop(
    const float* __restrict__ tin, float* __restrict__ tout,
    const int* __restrict__ rowptr, const int* __restrict__ cnt,
    const int2* __restrict__ edges, int nwaves) {
  int wid = (blockIdx.x << 2) + (threadIdx.x >> 6);
  if (wid >= nwaves) return;
  int lane = threadIdx.x & 63;
  int b = wid / NN;
  int n = wid - b * NN;
  int s = rowptr[n];
  int e = s + cnt[n];
  const float* base = tin + (size_t)b * NN * NC;
  float acc = 0.0f;
  for (int j = s; j < e; ++j) {
    int2 ed = edges[j];
    acc += __int_as_float(ed.y) * base[(size_t)ed.x * NC + lane];
  }
  tout[((size_t)b * NN + n) * NC + lane] = acc;
}

// ---- fused GEMM: out = [x|tx1|ptx1] @ Wc + bias ----------------------------
// tile 128 rows x 64 cols, 256 threads, 8x4 micro-tile. ptx1 may alias out
// (no __restrict__ there): each block stages all its rows to LDS before any
// write, and blocks touch disjoint row ranges.
__global__ __launch_bounds__(256) void cheb_gemm(
    const float* __restrict__ x, const float* __restrict__ tx1,
    const float* ptx1, const float* __restrict__ wc,
    const float* __restrict__ bias, float* out, int nrows) {
  __shared__ float At[64][132];   // [k][r], pad 132 -> conflict-free b128 reads
  __shared__ float Ws[64][64];    // [k][o]
  int tid = threadIdx.x;
  int tx = tid & 15;              // cols 4*tx .. 4*tx+3
  int ty = tid >> 4;              // rows 8*ty .. 8*ty+7
  size_t row0 = (size_t)blockIdx.x * 128;
  float acc[8][4];
#pragma unroll
  for (int i = 0; i < 8; ++i)
#pragma unroll
    for (int j = 0; j < 4; ++j) acc[i][j] = 0.0f;

  for (int ch = 0; ch < 3; ++ch) {
    const float* src = (ch == 0) ? x : ((ch == 1) ? tx1 : ptx1);
    {
      int k4 = (tid & 15) * 4;
      int rb = tid >> 4;
#pragma unroll
      for (int rr = 0; rr < 8; ++rr) {
        int r = rb + rr * 16;
        if (row0 + r < (size_t)nrows) {
          float4 v = *(const float4*)&src[(row0 + r) * NC + k4];
          At[k4 + 0][r] = v.x;
          At[k4 + 1][r] = v.y;
          At[k4 + 2][r] = v.z;
          At[k4 + 3][r] = v.w;
        } else {
          At[k4 + 0][r] = 0.0f;
          At[k4 + 1][r] = 0.0f;
          At[k4 + 2][r] = 0.0f;
          At[k4 + 3][r] = 0.0f;
        }
      }
#pragma unroll
      for (int ww = 0; ww < 4; ++ww) {
        int e4 = tid + 256 * ww;
        int k = e4 >> 4;
        int o4 = (e4 & 15) * 4;
        *(float4*)&Ws[k][o4] = *(const float4*)&wc[ch * 4096 + k * 64 + o4];
      }
    }
    __syncthreads();
#pragma unroll 2
    for (int k = 0; k < 64; ++k) {
      float4 wv = *(float4*)&Ws[k][tx * 4];
      float4 a0 = *(float4*)&At[k][ty * 8];
      float4 a1 = *(float4*)&At[k][ty * 8 + 4];
      float av[8] = {a0.x, a0.y, a0.z, a0.w, a1.x, a1.y, a1.z, a1.w};
      float wvv[4] = {wv.x, wv.y, wv.z, wv.w};
#pragma unroll
      for (int i = 0; i < 8; ++i)
#pragma unroll
        for (int j = 0; j < 4; ++j) acc[i][j] += av[i] * wvv[j];
    }
    __syncthreads();
  }
  float bb[4];
  {
    float4 bv = *(const float4*)&bias[tx * 4];
    bb[0] = bv.x; bb[1] = bv.y; bb[2] = bv.z; bb[3] = bv.w;
  }
#pragma unroll
  for (int i = 0; i < 8; ++i) {
    size_t r = row0 + ty * 8 + i;
    if (r >= (size_t)nrows) continue;
    float4 o = make_float4(acc[i][0] + bb[0], acc[i][1] + bb[1],
                           acc[i][2] + bb[2], acc[i][3] + bb[3]);
    *(float4*)&out[r * NC + tx * 4] = o;
  }
}

extern "C" void kernel_launch(void* const* d_in, const int* in_sizes, int n_in,
                              void* d_out, int out_size, void* d_ws, size_t ws_size,
                              hipStream_t stream) {
  (void)in_sizes; (void)n_in; (void)out_size;
  const float* x    = (const float*)d_in[0];
  const float* w    = (const float*)d_in[1];
  const float* bias = (const float*)d_in[2];
  const int*   ei   = (const int*)d_in[3];
  float* out = (float*)d_out;
  char* ws = (char*)d_ws;

  size_t off = 0;
  auto alloc = [&](size_t bytes) -> void* {
    void* p = (void*)(ws + off);
    off = (off + bytes + 255) & ~(size_t)255;
    return p;
  };
  // small buffers FIRST so they stay in-bounds for any plausible ws_size
  int* cnt      = (int*)alloc((size_t)(NN + 1) * sizeof(int));
  int* total    = cnt + NN;
  int* rowptr   = (int*)alloc((size_t)NN * sizeof(int));
  int* cur      = (int*)alloc((size_t)NN * sizeof(int));
  float* dinv   = (float*)alloc((size_t)NN * sizeof(float));
  int2* edges   = (int2*)alloc((size_t)NE * sizeof(int2));
  float* wcb    = (float*)alloc((size_t)3 * NC * NC * sizeof(float));
  size_t small_end = off;

  // shared setup
  hipMemsetAsync(cnt, 0, (NN + 1) * sizeof(int), stream);  // cnt + total
  cheb_count  <<<(NE + 255) / 256, 256, 0, stream>>>(ei, cnt);
  cheb_offsets<<<(NN + 255) / 256, 256, 0, stream>>>(cnt, dinv, rowptr, cur, total);
  cheb_scatter<<<(NE + 255) / 256, 256, 0, stream>>>(ei, dinv, cur, edges);
  cheb_wc     <<<(NC * NC + 255) / 256, 256, 0, stream>>>(w, wcb);

  const size_t fieldB = (size_t)NB * NN * NC * sizeof(float);  // 102.4 MB
  const size_t perbB  = (size_t)NN * NC * sizeof(float);       // 12.8 MB

  if (ws_size >= small_end + 2 * fieldB + 256) {
    // Tier A2: tx1 + ptx1 both in ws
    float* tx1  = (float*)alloc(fieldB);
    float* ptx1 = (float*)alloc(fieldB);
    cheb_prop<<<(NB * NN) / 4, 256, 0, stream>>>(x, tx1, rowptr, cnt, edges, NB * NN);
    cheb_prop<<<(NB * NN) / 4, 256, 0, stream>>>(tx1, ptx1, rowptr, cnt, edges, NB * NN);
    cheb_gemm<<<(NB * NN) / 128, 256, 0, stream>>>(x, tx1, ptx1, wcb, bias, out, NB * NN);
  } else if (ws_size >= small_end + fieldB + 256) {
    // Tier A1: tx1 in ws, ptx1 staged through out (gemm handles the alias)
    float* tx1 = (float*)alloc(fieldB);
    cheb_prop<<<(NB * NN) / 4, 256, 0, stream>>>(x, tx1, rowptr, cnt, edges, NB * NN);
    cheb_prop<<<(NB * NN) / 4, 256, 0, stream>>>(tx1, out, rowptr, cnt, edges, NB * NN);
    cheb_gemm<<<(NB * NN) / 128, 256, 0, stream>>>(x, tx1, out, wcb, bias, out, NB * NN);
  } else if (ws_size >= small_end + 2 * perbB + 256) {
    // Tier B: per-batch, both fields in ws
    float* tx1b  = (float*)alloc(perbB);
    float* ptx1b = (float*)alloc(perbB);
    for (int b = 0; b < NB; ++b) {
      const float* xb = x + (size_t)b * NN * NC;
      float* outb = out + (size_t)b * NN * NC;
      cheb_prop<<<(NN + 3) / 4, 256, 0, stream>>>(xb, tx1b, rowptr, cnt, edges, NN);
      cheb_prop<<<(NN + 3) / 4, 256, 0, stream>>>(tx1b, ptx1b, rowptr, cnt, edges, NN);
      cheb_gemm<<<(NN + 127) / 128, 256, 0, stream>>>(xb, tx1b, ptx1b, wcb, bias, outb, NN);
    }
  } else {
    // Tier C: per-batch, ptx1 staged through out slice (gemm handles alias)
    float* tx1b = (float*)alloc(perbB);
    for (int b = 0; b < NB; ++b) {
      const float* xb = x + (size_t)b * NN * NC;
      float* outb = out + (size_t)b * NN * NC;
      cheb_prop<<<(NN + 3) / 4, 256, 0, stream>>>(xb, tx1b, rowptr, cnt, edges, NN);
      cheb_prop<<<(NN + 3) / 4, 256, 0, stream>>>(tx1b, outb, rowptr, cnt, edges, NN);
      cheb_gemm<<<(NN + 127) / 128, 256, 0, stream>>>(xb, tx1b, outb, wcb, bias, outb, NN);
    }
  }
}

// Round 4
// 639.915 us; speedup vs baseline: 1.6177x; 1.6177x over previous
//
#include <hip/hip_runtime.h>

#define NB 8
#define NN 50000
#define NC 64
#define NE 400000

__device__ __forceinline__ void fma4(float4& a, float s, const float4& v) {
  a.x = fmaf(s, v.x, a.x); a.y = fmaf(s, v.y, a.y);
  a.z = fmaf(s, v.z, a.z); a.w = fmaf(s, v.w, a.w);
}

// ---- CSR build --------------------------------------------------------------
__global__ void cheb_count(const int* __restrict__ ei, int* __restrict__ cnt) {
  int e = blockIdx.x * blockDim.x + threadIdx.x;
  if (e >= NE) return;
  int r = ei[e], c = ei[NE + e];
  if (r != c) atomicAdd(&cnt[r], 1);
}

__global__ void cheb_offsets(const int* __restrict__ cnt, float* __restrict__ dinv,
                             int* __restrict__ rowptr, int* __restrict__ cur,
                             int* __restrict__ total) {
  int n = blockIdx.x * blockDim.x + threadIdx.x;
  if (n >= NN) return;
  int c = cnt[n];
  dinv[n] = (c > 0) ? rsqrtf((float)c) : 0.0f;
  int s = atomicAdd(total, c);   // bucket order irrelevant for a sum: no scan needed
  rowptr[n] = s;
  cur[n] = s;
}

__global__ void cheb_scatter(const int* __restrict__ ei, const float* __restrict__ dinv,
                             int* __restrict__ cur, int2* __restrict__ edges) {
  int e = blockIdx.x * blockDim.x + threadIdx.x;
  if (e >= NE) return;
  int r = ei[e], c = ei[NE + e];
  if (r == c) return;
  int pos = atomicAdd(&cur[r], 1);
  float lap = -dinv[r] * dinv[c];
  edges[pos] = make_int2(c, __float_as_int(lap));
}

// ---- Wc = [W0 - W2; W1; 2*W2] ----------------------------------------------
__global__ void cheb_wc(const float* __restrict__ w, float* __restrict__ wc) {
  int i = blockIdx.x * blockDim.x + threadIdx.x;
  if (i >= NC * NC) return;
  float w0 = w[i];
  float w1 = w[NC * NC + i];
  float w2 = w[2 * NC * NC + i];
  wc[i] = w0 - w2;
  wc[NC * NC + i] = w1;
  wc[2 * NC * NC + i] = 2.0f * w2;
}

// ---- prop8: all 8 batches per wave, one wave per node ----------------------
// lane = (bg:2)(cq:4): handles channels cq*4..cq*4+3 for b=bg and b=bg+4.
// Per edge: 2 dwordx4 gathers (1KB each). Edges loaded once per 64 into lanes
// and broadcast via __shfl. 4-edge unroll -> 8 gathers in flight.
// Layouts via strides: bnc = (colS=64, bS=NN*64); nbc = (colS=512, bS=64).
__global__ __launch_bounds__(256) void cheb_prop8(
    const float* __restrict__ tin, float* __restrict__ tout,
    const int* __restrict__ rowptr, const int* __restrict__ cnt,
    const int2* __restrict__ edges,
    long icolS, long ibS, long ocolS, long obS) {
  int n = (blockIdx.x << 2) + (threadIdx.x >> 6);
  int lane = threadIdx.x & 63;
  int cq4 = (lane & 15) * 4;
  int bg  = lane >> 4;
  int s = rowptr[n];
  int e = s + cnt[n];
  const float* t0 = tin + (size_t)bg * ibS + cq4;
  const float* t1 = tin + (size_t)(bg + 4) * ibS + cq4;
  float4 acc0 = make_float4(0.f, 0.f, 0.f, 0.f);
  float4 acc1 = make_float4(0.f, 0.f, 0.f, 0.f);

  int jc = s;
  while (jc < e) {
    int take = e - jc; if (take > 64) take = 64;
    int idx = jc + lane; if (idx > e - 1) idx = e - 1;
    int2 myed = edges[idx];   // one vector load covers up to 64 edges
    int m = 0;
    for (; m + 4 <= take; m += 4) {
      int   c0 = __shfl(myed.x, m + 0, 64);
      float l0 = __int_as_float(__shfl(myed.y, m + 0, 64));
      int   c1 = __shfl(myed.x, m + 1, 64);
      float l1 = __int_as_float(__shfl(myed.y, m + 1, 64));
      int   c2 = __shfl(myed.x, m + 2, 64);
      float l2 = __int_as_float(__shfl(myed.y, m + 2, 64));
      int   c3 = __shfl(myed.x, m + 3, 64);
      float l3 = __int_as_float(__shfl(myed.y, m + 3, 64));
      float4 a0 = *(const float4*)&t0[(size_t)c0 * icolS];
      float4 b0 = *(const float4*)&t1[(size_t)c0 * icolS];
      float4 a1 = *(const float4*)&t0[(size_t)c1 * icolS];
      float4 b1 = *(const float4*)&t1[(size_t)c1 * icolS];
      float4 a2 = *(const float4*)&t0[(size_t)c2 * icolS];
      float4 b2 = *(const float4*)&t1[(size_t)c2 * icolS];
      float4 a3 = *(const float4*)&t0[(size_t)c3 * icolS];
      float4 b3 = *(const float4*)&t1[(size_t)c3 * icolS];
      fma4(acc0, l0, a0); fma4(acc1, l0, b0);
      fma4(acc0, l1, a1); fma4(acc1, l1, b1);
      fma4(acc0, l2, a2); fma4(acc1, l2, b2);
      fma4(acc0, l3, a3); fma4(acc1, l3, b3);
    }
    for (; m < take; ++m) {
      int   c0 = __shfl(myed.x, m, 64);
      float l0 = __int_as_float(__shfl(myed.y, m, 64));
      float4 a0 = *(const float4*)&t0[(size_t)c0 * icolS];
      float4 b0 = *(const float4*)&t1[(size_t)c0 * icolS];
      fma4(acc0, l0, a0); fma4(acc1, l0, b0);
    }
    jc += take;
  }
  float* q = tout + (size_t)n * ocolS + cq4;
  *(float4*)&q[(size_t)bg * obS]       = acc0;
  *(float4*)&q[(size_t)(bg + 4) * obS] = acc1;
}

// ---- old per-(b,n)-wave prop, kept for small-ws fallback tiers -------------
__global__ __launch_bounds__(256) void cheb_prop(
    const float* __restrict__ tin, float* __restrict__ tout,
    const int* __restrict__ rowptr, const int* __restrict__ cnt,
    const int2* __restrict__ edges, int nwaves) {
  int wid = (blockIdx.x << 2) + (threadIdx.x >> 6);
  if (wid >= nwaves) return;
  int lane = threadIdx.x & 63;
  int b = wid / NN;
  int n = wid - b * NN;
  int s = rowptr[n];
  int e = s + cnt[n];
  const float* base = tin + (size_t)b * NN * NC;
  float acc = 0.0f;
  for (int j = s; j < e; ++j) {
    int2 ed = edges[j];
    acc += __int_as_float(ed.y) * base[(size_t)ed.x * NC + lane];
  }
  tout[((size_t)b * NN + n) * NC + lane] = acc;
}

// ---- fused GEMM: out = [x|tx1|ptx1] @ Wc + bias ----------------------------
// 128x64 tile, 256 threads, 8x4 micro-tile. Row-major At (broadcast reads are
// conflict-free), register-prefetch pipeline across the 3 K-chunks.
// ptx1 may alias out: all reads of a block's rows happen before its writes,
// and blocks own disjoint row ranges.
__global__ __launch_bounds__(256) void cheb_gemm2(
    const float* __restrict__ x, long xs_n, long xs_b,
    const float* __restrict__ tx1, long ts_n, long ts_b,
    const float* ptx1, long ps_n, long ps_b,
    const float* __restrict__ wc, const float* __restrict__ bias,
    float* out, int nrows) {
  __shared__ float At[128][64];   // [r][k] row-major
  __shared__ float Ws[64][64];    // [k][o]
  int tid = threadIdx.x;
  int tx = tid & 15;              // cols 4*tx..+3
  int ty = tid >> 4;              // rows 8*ty..+7
  long row0 = (long)blockIdx.x * 128;
  int b0 = (int)(row0 / NN);
  int n0 = (int)(row0 - (long)b0 * NN);
  int sk4 = (tid & 15) * 4;       // staging k offset
  int srb = tid >> 4;             // staging row base

  const float* sp[3] = {x, tx1, ptx1};
  long sn[3] = {xs_n, ts_n, ps_n};
  long sb[3] = {xs_b, ts_b, ps_b};

  float4 pa[8], pw[4];
  auto fetch = [&](int ch) {
    const float* s0 = sp[ch];
    long snS = sn[ch], sbS = sb[ch];
#pragma unroll
    for (int rr = 0; rr < 8; ++rr) {
      int roff = srb + rr * 16;
      if (row0 + roff < nrows) {
        int nn = n0 + roff, bb = b0;
        if (nn >= NN) { bb++; nn -= NN; }
        pa[rr] = *(const float4*)&s0[(size_t)nn * snS + (size_t)bb * sbS + sk4];
      } else {
        pa[rr] = make_float4(0.f, 0.f, 0.f, 0.f);
      }
    }
#pragma unroll
    for (int ww = 0; ww < 4; ++ww) {
      int e4 = tid + 256 * ww;
      int k = e4 >> 4, o4 = (e4 & 15) * 4;
      pw[ww] = *(const float4*)&wc[ch * 4096 + k * 64 + o4];
    }
  };
  auto commit = [&]() {
#pragma unroll
    for (int rr = 0; rr < 8; ++rr)
      *(float4*)&At[srb + rr * 16][sk4] = pa[rr];
#pragma unroll
    for (int ww = 0; ww < 4; ++ww) {
      int e4 = tid + 256 * ww;
      int k = e4 >> 4, o4 = (e4 & 15) * 4;
      *(float4*)&Ws[k][o4] = pw[ww];
    }
  };

  float4 acc[8];
#pragma unroll
  for (int i = 0; i < 8; ++i) acc[i] = make_float4(0.f, 0.f, 0.f, 0.f);

  fetch(0);
  commit();
  for (int ch = 0; ch < 3; ++ch) {
    __syncthreads();
    if (ch < 2) fetch(ch + 1);   // loads in flight during compute
#pragma unroll 4
    for (int k4 = 0; k4 < 16; ++k4) {
      float4 w0 = *(float4*)&Ws[k4 * 4 + 0][tx * 4];
      float4 w1 = *(float4*)&Ws[k4 * 4 + 1][tx * 4];
      float4 w2 = *(float4*)&Ws[k4 * 4 + 2][tx * 4];
      float4 w3 = *(float4*)&Ws[k4 * 4 + 3][tx * 4];
#pragma unroll
      for (int i = 0; i < 8; ++i) {
        float4 a = *(float4*)&At[ty * 8 + i][k4 * 4];  // 16-lane broadcast
        fma4(acc[i], a.x, w0);
        fma4(acc[i], a.y, w1);
        fma4(acc[i], a.z, w2);
        fma4(acc[i], a.w, w3);
      }
    }
    __syncthreads();
    if (ch < 2) commit();
  }

  float4 bb4 = *(const float4*)&bias[tx * 4];
#pragma unroll
  for (int i = 0; i < 8; ++i) {
    int roff = ty * 8 + i;
    if (row0 + roff >= nrows) continue;
    int nn = n0 + roff, bb = b0;
    if (nn >= NN) { bb++; nn -= NN; }
    float4 o = make_float4(acc[i].x + bb4.x, acc[i].y + bb4.y,
                           acc[i].z + bb4.z, acc[i].w + bb4.w);
    *(float4*)&out[((size_t)bb * NN + nn) * NC + tx * 4] = o;
  }
}

extern "C" void kernel_launch(void* const* d_in, const int* in_sizes, int n_in,
                              void* d_out, int out_size, void* d_ws, size_t ws_size,
                              hipStream_t stream) {
  (void)in_sizes; (void)n_in; (void)out_size;
  const float* x    = (const float*)d_in[0];
  const float* w    = (const float*)d_in[1];
  const float* bias = (const float*)d_in[2];
  const int*   ei   = (const int*)d_in[3];
  float* out = (float*)d_out;
  char* ws = (char*)d_ws;

  size_t off = 0;
  auto alloc = [&](size_t bytes) -> void* {
    void* p = (void*)(ws + off);
    off = (off + bytes + 255) & ~(size_t)255;
    return p;
  };
  // small buffers FIRST
  int* cnt      = (int*)alloc((size_t)(NN + 1) * sizeof(int));
  int* total    = cnt + NN;
  int* rowptr   = (int*)alloc((size_t)NN * sizeof(int));
  int* cur      = (int*)alloc((size_t)NN * sizeof(int));
  float* dinv   = (float*)alloc((size_t)NN * sizeof(float));
  int2* edges   = (int2*)alloc((size_t)NE * sizeof(int2));
  float* wcb    = (float*)alloc((size_t)3 * NC * NC * sizeof(float));
  size_t small_end = off;

  hipMemsetAsync(cnt, 0, (NN + 1) * sizeof(int), stream);
  cheb_count  <<<(NE + 255) / 256, 256, 0, stream>>>(ei, cnt);
  cheb_offsets<<<(NN + 255) / 256, 256, 0, stream>>>(cnt, dinv, rowptr, cur, total);
  cheb_scatter<<<(NE + 255) / 256, 256, 0, stream>>>(ei, dinv, cur, edges);
  cheb_wc     <<<(NC * NC + 255) / 256, 256, 0, stream>>>(w, wcb);

  const size_t fieldB = (size_t)NB * NN * NC * sizeof(float);  // 102.4 MB
  const size_t perbB  = (size_t)NN * NC * sizeof(float);       // 12.8 MB
  const long BNC = (long)NN * NC;  // batch stride in bnc layout

  if (ws_size >= small_end + 2 * fieldB + 256) {
    // Tier A2: tx1 + ptx1 in ws, both nbc layout
    float* tx1  = (float*)alloc(fieldB);
    float* ptx1 = (float*)alloc(fieldB);
    cheb_prop8<<<NN / 4, 256, 0, stream>>>(x, tx1, rowptr, cnt, edges,
                                           64, BNC, 512, 64);
    cheb_prop8<<<NN / 4, 256, 0, stream>>>(tx1, ptx1, rowptr, cnt, edges,
                                           512, 64, 512, 64);
    cheb_gemm2<<<(NB * NN) / 128, 256, 0, stream>>>(
        x, 64, BNC, tx1, 512, 64, ptx1, 512, 64, wcb, bias, out, NB * NN);
  } else if (ws_size >= small_end + fieldB + 256) {
    // Tier A1: tx1 in ws (nbc), ptx1 staged through out (bnc; gemm handles alias)
    float* tx1 = (float*)alloc(fieldB);
    cheb_prop8<<<NN / 4, 256, 0, stream>>>(x, tx1, rowptr, cnt, edges,
                                           64, BNC, 512, 64);
    cheb_prop8<<<NN / 4, 256, 0, stream>>>(tx1, out, rowptr, cnt, edges,
                                           512, 64, 64, BNC);
    cheb_gemm2<<<(NB * NN) / 128, 256, 0, stream>>>(
        x, 64, BNC, tx1, 512, 64, out, 64, BNC, wcb, bias, out, NB * NN);
  } else if (ws_size >= small_end + 2 * perbB + 256) {
    // Tier B: per-batch, both fields in ws (bnc, b=0)
    float* tx1b  = (float*)alloc(perbB);
    float* ptx1b = (float*)alloc(perbB);
    for (int b = 0; b < NB; ++b) {
      const float* xb = x + (size_t)b * NN * NC;
      float* outb = out + (size_t)b * NN * NC;
      cheb_prop<<<(NN + 3) / 4, 256, 0, stream>>>(xb, tx1b, rowptr, cnt, edges, NN);
      cheb_prop<<<(NN + 3) / 4, 256, 0, stream>>>(tx1b, ptx1b, rowptr, cnt, edges, NN);
      cheb_gemm2<<<(NN + 127) / 128, 256, 0, stream>>>(
          xb, 64, 0, tx1b, 64, 0, ptx1b, 64, 0, wcb, bias, outb, NN);
    }
  } else {
    // Tier C: per-batch, ptx1 staged through out slice
    float* tx1b = (float*)alloc(perbB);
    for (int b = 0; b < NB; ++b) {
      const float* xb = x + (size_t)b * NN * NC;
      float* outb = out + (size_t)b * NN * NC;
      cheb_prop<<<(NN + 3) / 4, 256, 0, stream>>>(xb, tx1b, rowptr, cnt, edges, NN);
      cheb_prop<<<(NN + 3) / 4, 256, 0, stream>>>(tx1b, outb, rowptr, cnt, edges, NN);
      cheb_gemm2<<<(NN + 127) / 128, 256, 0, stream>>>(
          xb, 64, 0, tx1b, 64, 0, outb, 64, 0, wcb, bias, outb, NN);
    }
  }
}

// Round 5
// 390.685 us; speedup vs baseline: 2.6496x; 1.6379x over previous
//
#include <hip/hip_runtime.h>

#define NB 8
#define NN 50000
#define NC 64
#define NE 400000

typedef unsigned short us4 __attribute__((ext_vector_type(4)));
typedef unsigned short us8 __attribute__((ext_vector_type(8)));
typedef short s8v __attribute__((ext_vector_type(8)));   // bf16x8 MFMA operand
typedef float f4v __attribute__((ext_vector_type(4)));   // fp32x4 MFMA acc

__device__ __forceinline__ float bf2f(unsigned short u) {
  union { unsigned int i; float f; } v; v.i = ((unsigned int)u) << 16; return v.f;
}
__device__ __forceinline__ unsigned short f2bf(float f) {
  union { float f; unsigned int i; } v; v.f = f;
  unsigned int x = v.i;
  return (unsigned short)((x + 0x7FFFu + ((x >> 16) & 1u)) >> 16);  // RNE
}
__device__ __forceinline__ void fma4(float4& a, float s, const float4& v) {
  a.x = fmaf(s, v.x, a.x); a.y = fmaf(s, v.y, a.y);
  a.z = fmaf(s, v.z, a.z); a.w = fmaf(s, v.w, a.w);
}

// ---- CSR build --------------------------------------------------------------
__global__ void cheb_count(const int* __restrict__ ei, int* __restrict__ cnt) {
  int e = blockIdx.x * blockDim.x + threadIdx.x;
  if (e >= NE) return;
  int r = ei[e], c = ei[NE + e];
  if (r != c) atomicAdd(&cnt[r], 1);
}

__global__ void cheb_offsets(const int* __restrict__ cnt, float* __restrict__ dinv,
                             int* __restrict__ rowptr, int* __restrict__ cur,
                             int* __restrict__ total) {
  int n = blockIdx.x * blockDim.x + threadIdx.x;
  if (n >= NN) return;
  int c = cnt[n];
  dinv[n] = (c > 0) ? rsqrtf((float)c) : 0.0f;
  int s = atomicAdd(total, c);   // bucket order irrelevant for a sum
  rowptr[n] = s;
  cur[n] = s;
}

__global__ void cheb_scatter(const int* __restrict__ ei, const float* __restrict__ dinv,
                             int* __restrict__ cur, int2* __restrict__ edges) {
  int e = blockIdx.x * blockDim.x + threadIdx.x;
  if (e >= NE) return;
  int r = ei[e], c = ei[NE + e];
  if (r == c) return;
  int pos = atomicAdd(&cur[r], 1);
  float lap = -dinv[r] * dinv[c];
  edges[pos] = make_int2(c, __float_as_int(lap));
}

// ---- Wc fp32 (fallback path only) ------------------------------------------
__global__ void cheb_wc(const float* __restrict__ w, float* __restrict__ wc) {
  int i = blockIdx.x * blockDim.x + threadIdx.x;
  if (i >= NC * NC) return;
  float w0 = w[i];
  float w1 = w[NC * NC + i];
  float w2 = w[2 * NC * NC + i];
  wc[i] = w0 - w2;
  wc[NC * NC + i] = w1;
  wc[2 * NC * NC + i] = 2.0f * w2;
}

// ---- pack Wc into bf16 B-fragment order ------------------------------------
// pack[(((ks*4+nt)*64)+l)*8+jj] = Wc[ks*32+(l>>4)*8+jj][nt*16+(l&15)]
__global__ void cheb_wpack(const float* __restrict__ w, unsigned short* __restrict__ pack) {
  int t = blockIdx.x * blockDim.x + threadIdx.x;
  if (t >= 6 * 4 * 64 * 8) return;
  int jj = t & 7;
  int l  = (t >> 3) & 63;
  int nt = (t >> 9) & 3;
  int ks = t >> 11;
  int k = ks * 32 + ((l >> 4) * 8) + jj;     // 0..191
  int o = nt * 16 + (l & 15);                // 0..63
  int ki = k & 63, ch = k >> 6;
  float v;
  if (ch == 0)      v = w[ki * 64 + o] - w[2 * 4096 + ki * 64 + o];
  else if (ch == 1) v = w[4096 + ki * 64 + o];
  else              v = 2.0f * w[2 * 4096 + ki * 64 + o];
  pack[t] = f2bf(v);
}

// ---- convert x (bnc fp32) -> xh (nbc bf16; node record = 1KB contiguous) ---
__global__ __launch_bounds__(256) void cheb_convert(
    const float* __restrict__ x, unsigned short* __restrict__ xh) {
  int t = blockIdx.x * blockDim.x + threadIdx.x;
  if (t >= NN * 128) return;
  int n = t >> 7;
  int rem = t & 127;
  int b = rem >> 4;
  int c4 = (rem & 15) * 4;
  float4 v = *(const float4*)&x[((size_t)b * NN + n) * 64 + c4];
  us4 o;
  o[0] = f2bf(v.x); o[1] = f2bf(v.y); o[2] = f2bf(v.z); o[3] = f2bf(v.w);
  *(us4*)&xh[(size_t)n * 512 + b * 64 + c4] = o;
}

// ---- prop1h: tx1h[n] = sum lap * xh[col]; one wave per node ----------------
// Per edge: ONE b128 gather (64 lanes x 16B = the whole 1KB nbc record).
// lane = (b:3)(ch8:3): 8 channels of one batch. 8-edge unroll.
__global__ __launch_bounds__(256) void cheb_prop1h(
    const unsigned short* __restrict__ tin, unsigned short* __restrict__ tout,
    const int* __restrict__ rowptr, const int* __restrict__ cnt,
    const int2* __restrict__ edges) {
  int n = (blockIdx.x << 2) + (threadIdx.x >> 6);
  if (n >= NN) return;
  int lane = threadIdx.x & 63;
  int s = rowptr[n], e = s + cnt[n];
  const unsigned short* tb = tin + lane * 8;
  float acc[8];
#pragma unroll
  for (int q = 0; q < 8; ++q) acc[q] = 0.0f;

  int jc = s;
  while (jc < e) {
    int take = e - jc; if (take > 64) take = 64;
    int2 myed = edges[jc + (lane < take ? lane : take - 1)];
    int m = 0;
    for (; m + 8 <= take; m += 8) {
      us8 v[8]; float lp[8];
#pragma unroll
      for (int u = 0; u < 8; ++u) {
        int c = __shfl(myed.x, m + u, 64);
        lp[u] = __int_as_float(__shfl(myed.y, m + u, 64));
        v[u] = *(const us8*)&tb[(size_t)c * 512];
      }
#pragma unroll
      for (int u = 0; u < 8; ++u)
#pragma unroll
        for (int q = 0; q < 8; ++q) acc[q] = fmaf(lp[u], bf2f(v[u][q]), acc[q]);
    }
    for (; m < take; ++m) {
      int c = __shfl(myed.x, m, 64);
      float l0 = __int_as_float(__shfl(myed.y, m, 64));
      us8 v = *(const us8*)&tb[(size_t)c * 512];
#pragma unroll
      for (int q = 0; q < 8; ++q) acc[q] = fmaf(l0, bf2f(v[q]), acc[q]);
    }
    jc += take;
  }
  us8 o;
#pragma unroll
  for (int q = 0; q < 8; ++q) o[q] = f2bf(acc[q]);
  *(us8*)&tout[(size_t)n * 512 + lane * 8] = o;
}

// ---- fused prop2 + MFMA GEMM -----------------------------------------------
// Each wave owns 32 rows (= 4 nodes x 8 batches, nbc row order rn=n*8+b):
//   stage xh/tx1h strips (contiguous 4KB each) -> LDS cols 0..63 / 64..127,
//   compute ptx1 rows by gathering tx1h -> LDS cols 128..191,
//   6 ksteps x (2 M-tiles x 4 N-tiles) mfma_f32_16x16x32_bf16, bias, store.
// LDS region is wave-private -> NO barriers. Row stride 200 (400B) keeps
// A-frag b128 reads 16B-aligned and spread across banks.
__global__ __launch_bounds__(256) void cheb_fused(
    const unsigned short* __restrict__ xh, const unsigned short* __restrict__ tx1h,
    const int* __restrict__ rowptr, const int* __restrict__ cnt,
    const int2* __restrict__ edges, const unsigned short* __restrict__ pack,
    const float* __restrict__ bias, float* __restrict__ out) {
  __shared__ unsigned short Ab[4][32][200];
  int w = threadIdx.x >> 6, lane = threadIdx.x & 63;
  int row0 = blockIdx.x * 128 + w * 32;
  int n0 = row0 >> 3;
  unsigned short (*A)[200] = Ab[w];

  // stage xh / tx1h strips (each strip is 4KB contiguous in nbc layout)
  {
    const unsigned short* sx = xh   + (size_t)row0 * 64 + lane * 32;
    const unsigned short* st = tx1h + (size_t)row0 * 64 + lane * 32;
    int r = lane >> 1, kk = (lane & 1) * 32;
#pragma unroll
    for (int q = 0; q < 4; ++q) {
      *(us8*)&A[r][kk + q * 8]      = *(const us8*)&sx[q * 8];
      *(us8*)&A[r][64 + kk + q * 8] = *(const us8*)&st[q * 8];
    }
  }

  // prop2 for the wave's 4 nodes -> LDS cols 128..191
  const unsigned short* tb = tx1h + lane * 8;
  for (int j = 0; j < 4; ++j) {
    int n = n0 + j;
    int s = rowptr[n], e = s + cnt[n];
    float acc8[8];
#pragma unroll
    for (int q = 0; q < 8; ++q) acc8[q] = 0.0f;
    int jc = s;
    while (jc < e) {
      int take = e - jc; if (take > 64) take = 64;
      int2 myed = edges[jc + (lane < take ? lane : take - 1)];
      int m = 0;
      for (; m + 8 <= take; m += 8) {
        us8 v[8]; float lp[8];
#pragma unroll
        for (int u = 0; u < 8; ++u) {
          int c = __shfl(myed.x, m + u, 64);
          lp[u] = __int_as_float(__shfl(myed.y, m + u, 64));
          v[u] = *(const us8*)&tb[(size_t)c * 512];
        }
#pragma unroll
        for (int u = 0; u < 8; ++u)
#pragma unroll
          for (int q = 0; q < 8; ++q) acc8[q] = fmaf(lp[u], bf2f(v[u][q]), acc8[q]);
      }
      for (; m < take; ++m) {
        int c = __shfl(myed.x, m, 64);
        float l0 = __int_as_float(__shfl(myed.y, m, 64));
        us8 v = *(const us8*)&tb[(size_t)c * 512];
#pragma unroll
        for (int q = 0; q < 8; ++q) acc8[q] = fmaf(l0, bf2f(v[q]), acc8[q]);
      }
      jc += take;
    }
    us8 o;
#pragma unroll
    for (int q = 0; q < 8; ++q) o[q] = f2bf(acc8[q]);
    *(us8*)&A[j * 8 + (lane >> 3)][128 + (lane & 7) * 8] = o;
  }

  // MFMA: 2 M-tiles x 4 N-tiles, K=192 in 6 steps of 32
  f4v acc[2][4];
#pragma unroll
  for (int mt = 0; mt < 2; ++mt)
#pragma unroll
    for (int nt = 0; nt < 4; ++nt) acc[mt][nt] = (f4v){0.f, 0.f, 0.f, 0.f};

  int am = lane & 15, aq = (lane >> 4) * 8;
#pragma unroll
  for (int ks = 0; ks < 6; ++ks) {
    s8v a0 = *(const s8v*)&A[am][ks * 32 + aq];
    s8v a1 = *(const s8v*)&A[16 + am][ks * 32 + aq];
#pragma unroll
    for (int nt = 0; nt < 4; ++nt) {
      s8v b = *(const s8v*)&pack[(((size_t)(ks * 4 + nt) * 64) + lane) * 8];
      acc[0][nt] = __builtin_amdgcn_mfma_f32_16x16x32_bf16(a0, b, acc[0][nt], 0, 0, 0);
      acc[1][nt] = __builtin_amdgcn_mfma_f32_16x16x32_bf16(a1, b, acc[1][nt], 0, 0, 0);
    }
  }

  // epilogue: + bias, store to out (bnc fp32). C/D: row=(lane>>4)*4+r, col=lane&15
  float bv[4];
#pragma unroll
  for (int nt = 0; nt < 4; ++nt) bv[nt] = bias[nt * 16 + (lane & 15)];
#pragma unroll
  for (int mt = 0; mt < 2; ++mt)
#pragma unroll
    for (int r = 0; r < 4; ++r) {
      int rl = mt * 16 + (lane >> 4) * 4 + r;
      int rn = row0 + rl;
      int b = rn & 7, nn = rn >> 3;
      float* orow = &out[((size_t)b * NN + nn) * 64 + (lane & 15)];
#pragma unroll
      for (int nt = 0; nt < 4; ++nt) orow[nt * 16] = acc[mt][nt][r] + bv[nt];
    }
}

// ---- fallback fp32 kernels (small-ws tiers) --------------------------------
__global__ __launch_bounds__(256) void cheb_prop(
    const float* __restrict__ tin, float* __restrict__ tout,
    const int* __restrict__ rowptr, const int* __restrict__ cnt,
    const int2* __restrict__ edges, int nwaves) {
  int wid = (blockIdx.x << 2) + (threadIdx.x >> 6);
  if (wid >= nwaves) return;
  int lane = threadIdx.x & 63;
  int b = wid / NN;
  int n = wid - b * NN;
  int s = rowptr[n];
  int e = s + cnt[n];
  const float* base = tin + (size_t)b * NN * NC;
  float acc = 0.0f;
  for (int j = s; j < e; ++j) {
    int2 ed = edges[j];
    acc += __int_as_float(ed.y) * base[(size_t)ed.x * NC + lane];
  }
  tout[((size_t)b * NN + n) * NC + lane] = acc;
}

__global__ __launch_bounds__(256) void cheb_gemm2(
    const float* __restrict__ x, const float* __restrict__ tx1,
    const float* ptx1, const float* __restrict__ wc,
    const float* __restrict__ bias, float* out, int nrows) {
  __shared__ float At[128][64];
  __shared__ float Ws[64][64];
  int tid = threadIdx.x;
  int tx = tid & 15;
  int ty = tid >> 4;
  long row0 = (long)blockIdx.x * 128;
  int sk4 = (tid & 15) * 4;
  int srb = tid >> 4;
  const float* sp[3] = {x, tx1, ptx1};
  float4 pa[8], pw[4];
  auto fetch = [&](int ch) {
    const float* s0 = sp[ch];
#pragma unroll
    for (int rr = 0; rr < 8; ++rr) {
      int roff = srb + rr * 16;
      if (row0 + roff < nrows)
        pa[rr] = *(const float4*)&s0[(size_t)(row0 + roff) * NC + sk4];
      else
        pa[rr] = make_float4(0.f, 0.f, 0.f, 0.f);
    }
#pragma unroll
    for (int ww = 0; ww < 4; ++ww) {
      int e4 = tid + 256 * ww;
      pw[ww] = *(const float4*)&wc[ch * 4096 + (e4 >> 4) * 64 + (e4 & 15) * 4];
    }
  };
  auto commit = [&]() {
#pragma unroll
    for (int rr = 0; rr < 8; ++rr)
      *(float4*)&At[srb + rr * 16][sk4] = pa[rr];
#pragma unroll
    for (int ww = 0; ww < 4; ++ww) {
      int e4 = tid + 256 * ww;
      *(float4*)&Ws[e4 >> 4][(e4 & 15) * 4] = pw[ww];
    }
  };
  float4 acc[8];
#pragma unroll
  for (int i = 0; i < 8; ++i) acc[i] = make_float4(0.f, 0.f, 0.f, 0.f);
  fetch(0);
  commit();
  for (int ch = 0; ch < 3; ++ch) {
    __syncthreads();
    if (ch < 2) fetch(ch + 1);
#pragma unroll 4
    for (int k4 = 0; k4 < 16; ++k4) {
      float4 w0 = *(float4*)&Ws[k4 * 4 + 0][tx * 4];
      float4 w1 = *(float4*)&Ws[k4 * 4 + 1][tx * 4];
      float4 w2 = *(float4*)&Ws[k4 * 4 + 2][tx * 4];
      float4 w3 = *(float4*)&Ws[k4 * 4 + 3][tx * 4];
#pragma unroll
      for (int i = 0; i < 8; ++i) {
        float4 a = *(float4*)&At[ty * 8 + i][k4 * 4];
        fma4(acc[i], a.x, w0);
        fma4(acc[i], a.y, w1);
        fma4(acc[i], a.z, w2);
        fma4(acc[i], a.w, w3);
      }
    }
    __syncthreads();
    if (ch < 2) commit();
  }
  float4 bb4 = *(const float4*)&bias[tx * 4];
#pragma unroll
  for (int i = 0; i < 8; ++i) {
    long r = row0 + ty * 8 + i;
    if (r >= nrows) continue;
    float4 o = make_float4(acc[i].x + bb4.x, acc[i].y + bb4.y,
                           acc[i].z + bb4.z, acc[i].w + bb4.w);
    *(float4*)&out[(size_t)r * NC + tx * 4] = o;
  }
}

extern "C" void kernel_launch(void* const* d_in, const int* in_sizes, int n_in,
                              void* d_out, int out_size, void* d_ws, size_t ws_size,
                              hipStream_t stream) {
  (void)in_sizes; (void)n_in; (void)out_size;
  const float* x    = (const float*)d_in[0];
  const float* w    = (const float*)d_in[1];
  const float* bias = (const float*)d_in[2];
  const int*   ei   = (const int*)d_in[3];
  float* out = (float*)d_out;
  char* ws = (char*)d_ws;

  size_t off = 0;
  auto alloc = [&](size_t bytes) -> void* {
    void* p = (void*)(ws + off);
    off = (off + bytes + 255) & ~(size_t)255;
    return p;
  };
  int* cnt      = (int*)alloc((size_t)(NN + 1) * sizeof(int));
  int* total    = cnt + NN;
  int* rowptr   = (int*)alloc((size_t)NN * sizeof(int));
  int* cur      = (int*)alloc((size_t)NN * sizeof(int));
  float* dinv   = (float*)alloc((size_t)NN * sizeof(float));
  int2* edges   = (int2*)alloc((size_t)NE * sizeof(int2));
  float* wcb    = (float*)alloc((size_t)3 * NC * NC * sizeof(float));
  unsigned short* pack = (unsigned short*)alloc((size_t)6 * 4 * 64 * 8 * sizeof(unsigned short));
  size_t small_end = off;

  hipMemsetAsync(cnt, 0, (NN + 1) * sizeof(int), stream);
  cheb_count  <<<(NE + 255) / 256, 256, 0, stream>>>(ei, cnt);
  cheb_offsets<<<(NN + 255) / 256, 256, 0, stream>>>(cnt, dinv, rowptr, cur, total);
  cheb_scatter<<<(NE + 255) / 256, 256, 0, stream>>>(ei, dinv, cur, edges);

  const size_t fieldHB = (size_t)NN * 512 * sizeof(unsigned short);  // 51.2 MB
  const size_t perbB   = (size_t)NN * NC * sizeof(float);            // 12.8 MB

  if (ws_size >= small_end + 2 * fieldHB + 256) {
    // Tier A: bf16 pipeline with fused prop2+MFMA GEMM
    unsigned short* xh   = (unsigned short*)alloc(fieldHB);
    unsigned short* tx1h = (unsigned short*)alloc(fieldHB);
    cheb_wpack  <<<(6 * 4 * 64 * 8 + 255) / 256, 256, 0, stream>>>(w, pack);
    cheb_convert<<<(NN * 128) / 256, 256, 0, stream>>>(x, xh);
    cheb_prop1h <<<NN / 4, 256, 0, stream>>>(xh, tx1h, rowptr, cnt, edges);
    cheb_fused  <<<(NB * NN) / 128, 256, 0, stream>>>(
        xh, tx1h, rowptr, cnt, edges, pack, bias, out);
  } else if (ws_size >= small_end + 2 * perbB + 256) {
    // Tier B: per-batch fp32 fallback
    cheb_wc<<<(NC * NC + 255) / 256, 256, 0, stream>>>(w, wcb);
    float* tx1b  = (float*)alloc(perbB);
    float* ptx1b = (float*)alloc(perbB);
    for (int b = 0; b < NB; ++b) {
      const float* xb = x + (size_t)b * NN * NC;
      float* outb = out + (size_t)b * NN * NC;
      cheb_prop<<<(NN + 3) / 4, 256, 0, stream>>>(xb, tx1b, rowptr, cnt, edges, NN);
      cheb_prop<<<(NN + 3) / 4, 256, 0, stream>>>(tx1b, ptx1b, rowptr, cnt, edges, NN);
      cheb_gemm2<<<(NN + 127) / 128, 256, 0, stream>>>(
          xb, tx1b, ptx1b, wcb, bias, outb, NN);
    }
  } else {
    // Tier C: per-batch fp32, ptx1 via out slice (gemm stages before writes)
    cheb_wc<<<(NC * NC + 255) / 256, 256, 0, stream>>>(w, wcb);
    float* tx1b = (float*)alloc(perbB);
    for (int b = 0; b < NB; ++b) {
      const float* xb = x + (size_t)b * NN * NC;
      float* outb = out + (size_t)b * NN * NC;
      cheb_prop<<<(NN + 3) / 4, 256, 0, stream>>>(xb, tx1b, rowptr, cnt, edges, NN);
      cheb_prop<<<(NN + 3) / 4, 256, 0, stream>>>(tx1b, outb, rowptr, cnt, edges, NN);
      cheb_gemm2<<<(NN + 127) / 128, 256, 0, stream>>>(
          xb, tx1b, outb, wcb, bias, outb, NN);
    }
  }
}

// Round 6
// 375.525 us; speedup vs baseline: 2.7566x; 1.0404x over previous
//
#include <hip/hip_runtime.h>

#define NB 8
#define NN 50000
#define NC 64
#define NE 400000

typedef unsigned short us4 __attribute__((ext_vector_type(4)));
typedef unsigned short us8 __attribute__((ext_vector_type(8)));
typedef short s8v __attribute__((ext_vector_type(8)));   // bf16x8 MFMA operand
typedef float f4v __attribute__((ext_vector_type(4)));   // fp32x4 MFMA acc / NT float4

__device__ __forceinline__ float bf2f(unsigned short u) {
  union { unsigned int i; float f; } v; v.i = ((unsigned int)u) << 16; return v.f;
}
__device__ __forceinline__ unsigned short f2bf(float f) {
  union { float f; unsigned int i; } v; v.f = f;
  unsigned int x = v.i;
  return (unsigned short)((x + 0x7FFFu + ((x >> 16) & 1u)) >> 16);  // RNE
}
__device__ __forceinline__ void fma4(float4& a, float s, const float4& v) {
  a.x = fmaf(s, v.x, a.x); a.y = fmaf(s, v.y, a.y);
  a.z = fmaf(s, v.z, a.z); a.w = fmaf(s, v.w, a.w);
}

// ---- CSR build --------------------------------------------------------------
__global__ void cheb_count(const int* __restrict__ ei, int* __restrict__ cnt) {
  int e = blockIdx.x * blockDim.x + threadIdx.x;
  if (e >= NE) return;
  int r = ei[e], c = ei[NE + e];
  if (r != c) atomicAdd(&cnt[r], 1);
}

__global__ void cheb_offsets(const int* __restrict__ cnt, float* __restrict__ dinv,
                             int* __restrict__ rowptr, int* __restrict__ cur,
                             int* __restrict__ total) {
  int n = blockIdx.x * blockDim.x + threadIdx.x;
  if (n >= NN) return;
  int c = cnt[n];
  dinv[n] = (c > 0) ? rsqrtf((float)c) : 0.0f;
  int s = atomicAdd(total, c);   // bucket order irrelevant for a sum
  rowptr[n] = s;
  cur[n] = s;
}

__global__ void cheb_scatter(const int* __restrict__ ei, const float* __restrict__ dinv,
                             int* __restrict__ cur, int2* __restrict__ edges) {
  int e = blockIdx.x * blockDim.x + threadIdx.x;
  if (e >= NE) return;
  int r = ei[e], c = ei[NE + e];
  if (r == c) return;
  int pos = atomicAdd(&cur[r], 1);
  float lap = -dinv[r] * dinv[c];
  edges[pos] = make_int2(c, __float_as_int(lap));
}

// ---- Wc fp32 (fallback path only) ------------------------------------------
__global__ void cheb_wc(const float* __restrict__ w, float* __restrict__ wc) {
  int i = blockIdx.x * blockDim.x + threadIdx.x;
  if (i >= NC * NC) return;
  float w0 = w[i];
  float w1 = w[NC * NC + i];
  float w2 = w[2 * NC * NC + i];
  wc[i] = w0 - w2;
  wc[NC * NC + i] = w1;
  wc[2 * NC * NC + i] = 2.0f * w2;
}

// ---- pack Wc into bf16 B-fragment order ------------------------------------
// pack[(((ks*4+nt)*64)+l)*8+jj] = Wc[ks*32+(l>>4)*8+jj][nt*16+(l&15)]
__global__ void cheb_wpack(const float* __restrict__ w, unsigned short* __restrict__ pack) {
  int t = blockIdx.x * blockDim.x + threadIdx.x;
  if (t >= 6 * 4 * 64 * 8) return;
  int jj = t & 7;
  int l  = (t >> 3) & 63;
  int nt = (t >> 9) & 3;
  int ks = t >> 11;
  int k = ks * 32 + ((l >> 4) * 8) + jj;     // 0..191
  int o = nt * 16 + (l & 15);                // 0..63
  int ki = k & 63, ch = k >> 6;
  float v;
  if (ch == 0)      v = w[ki * 64 + o] - w[2 * 4096 + ki * 64 + o];
  else if (ch == 1) v = w[4096 + ki * 64 + o];
  else              v = 2.0f * w[2 * 4096 + ki * 64 + o];
  pack[t] = f2bf(v);
}

// ---- convert x (bnc fp32) -> xh (nbc bf16; node record = 1KB contiguous) ---
__global__ __launch_bounds__(256) void cheb_convert(
    const float* __restrict__ x, unsigned short* __restrict__ xh) {
  int t = blockIdx.x * blockDim.x + threadIdx.x;
  if (t >= NN * 128) return;
  int n = t >> 7;
  int rem = t & 127;
  int b = rem >> 4;
  int c4 = (rem & 15) * 4;
  f4v v = __builtin_nontemporal_load((const f4v*)&x[((size_t)b * NN + n) * 64 + c4]);
  us4 o;
  o[0] = f2bf(v[0]); o[1] = f2bf(v[1]); o[2] = f2bf(v[2]); o[3] = f2bf(v[3]);
  *(us4*)&xh[(size_t)n * 512 + b * 64 + c4] = o;
}

// ---- prop1h: tx1h[n] = sum lap * xh[col]; one wave per node ----------------
// Per edge: ONE b128 gather (64 lanes x 16B = whole 1KB nbc record).
// Edges always processed in groups of 8 (clamped idx + lap=0 mask) so 8
// gathers are in flight even for low-degree nodes.
__global__ __launch_bounds__(256) void cheb_prop1h(
    const unsigned short* __restrict__ tin, unsigned short* __restrict__ tout,
    const int* __restrict__ rowptr, const int* __restrict__ cnt,
    const int2* __restrict__ edges) {
  int n = (blockIdx.x << 2) + (threadIdx.x >> 6);
  if (n >= NN) return;
  int lane = threadIdx.x & 63;
  int s = rowptr[n], e = s + cnt[n];
  const unsigned short* tb = tin + lane * 8;
  float acc[8];
#pragma unroll
  for (int q = 0; q < 8; ++q) acc[q] = 0.0f;

  int jc = s;
  while (jc < e) {
    int take = e - jc; if (take > 64) take = 64;
    int2 myed = edges[jc + (lane < take ? lane : take - 1)];
    for (int m = 0; m < take; m += 8) {
      us8 v[8]; float lp[8];
#pragma unroll
      for (int u = 0; u < 8; ++u) {
        int mu = (m + u < take) ? m + u : take - 1;
        int c = __shfl(myed.x, mu, 64);
        float l = __int_as_float(__shfl(myed.y, mu, 64));
        lp[u] = (m + u < take) ? l : 0.0f;
        v[u] = *(const us8*)&tb[(size_t)c * 512];
      }
#pragma unroll
      for (int u = 0; u < 8; ++u)
#pragma unroll
        for (int q = 0; q < 8; ++q) acc[q] = fmaf(lp[u], bf2f(v[u][q]), acc[q]);
    }
    jc += take;
  }
  us8 o;
#pragma unroll
  for (int q = 0; q < 8; ++q) o[q] = f2bf(acc[q]);
  *(us8*)&tout[(size_t)n * 512 + lane * 8] = o;
}

// ---- fused prop2 + MFMA GEMM -----------------------------------------------
// Each wave owns 32 rows (4 nodes x 8 batches, rn = n*8+b):
//   prop2: gather tx1h -> wave-private LDS tile P (only ptx1 needs LDS);
//   MFMA: 6 ksteps x (2 M x 4 N) 16x16x32_bf16; A-frags for ks 0..3 stream
//   straight from xh/tx1h global (single-use -> nontemporal), ks 4..5 from P.
// No barriers (P is wave-private). out stores nontemporal to keep L3 for the
// tx1h gather working set.
__global__ __launch_bounds__(256) void cheb_fused(
    const unsigned short* __restrict__ xh, const unsigned short* __restrict__ tx1h,
    const int* __restrict__ rowptr, const int* __restrict__ cnt,
    const int2* __restrict__ edges, const unsigned short* __restrict__ pack,
    const float* __restrict__ bias, float* __restrict__ out) {
  __shared__ unsigned short Pb[4][32][72];   // stride 72 shorts = 144B, 16B-aligned rows
  int w = threadIdx.x >> 6, lane = threadIdx.x & 63;
  int row0 = blockIdx.x * 128 + w * 32;
  int n0 = row0 >> 3;
  unsigned short (*P)[72] = Pb[w];

  // prop2 for the wave's 4 nodes -> P  (lane = (b:3)(ch8:3))
  const unsigned short* tb = tx1h + lane * 8;
  for (int j = 0; j < 4; ++j) {
    int n = n0 + j;
    int s = rowptr[n], e = s + cnt[n];
    float acc8[8];
#pragma unroll
    for (int q = 0; q < 8; ++q) acc8[q] = 0.0f;
    int jc = s;
    while (jc < e) {
      int take = e - jc; if (take > 64) take = 64;
      int2 myed = edges[jc + (lane < take ? lane : take - 1)];
      for (int m = 0; m < take; m += 8) {
        us8 v[8]; float lp[8];
#pragma unroll
        for (int u = 0; u < 8; ++u) {
          int mu = (m + u < take) ? m + u : take - 1;
          int c = __shfl(myed.x, mu, 64);
          float l = __int_as_float(__shfl(myed.y, mu, 64));
          lp[u] = (m + u < take) ? l : 0.0f;
          v[u] = *(const us8*)&tb[(size_t)c * 512];
        }
#pragma unroll
        for (int u = 0; u < 8; ++u)
#pragma unroll
          for (int q = 0; q < 8; ++q) acc8[q] = fmaf(lp[u], bf2f(v[u][q]), acc8[q]);
      }
      jc += take;
    }
    us8 o;
#pragma unroll
    for (int q = 0; q < 8; ++q) o[q] = f2bf(acc8[q]);
    *(us8*)&P[j * 8 + (lane >> 3)][(lane & 7) * 8] = o;
  }

  // MFMA: 2 M-tiles x 4 N-tiles, K=192 in 6 steps of 32
  f4v acc[2][4];
#pragma unroll
  for (int mt = 0; mt < 2; ++mt)
#pragma unroll
    for (int nt = 0; nt < 4; ++nt) acc[mt][nt] = (f4v){0.f, 0.f, 0.f, 0.f};

  int am = lane & 15, aq = (lane >> 4) * 8;
#pragma unroll
  for (int ks = 0; ks < 6; ++ks) {
    s8v a0, a1;
    if (ks < 2) {
      a0 = __builtin_nontemporal_load((const s8v*)&xh[(size_t)(row0 + am) * 64 + ks * 32 + aq]);
      a1 = __builtin_nontemporal_load((const s8v*)&xh[(size_t)(row0 + 16 + am) * 64 + ks * 32 + aq]);
    } else if (ks < 4) {
      a0 = __builtin_nontemporal_load((const s8v*)&tx1h[(size_t)(row0 + am) * 64 + (ks - 2) * 32 + aq]);
      a1 = __builtin_nontemporal_load((const s8v*)&tx1h[(size_t)(row0 + 16 + am) * 64 + (ks - 2) * 32 + aq]);
    } else {
      a0 = *(const s8v*)&P[am][(ks - 4) * 32 + aq];
      a1 = *(const s8v*)&P[16 + am][(ks - 4) * 32 + aq];
    }
#pragma unroll
    for (int nt = 0; nt < 4; ++nt) {
      s8v b = *(const s8v*)&pack[(((size_t)(ks * 4 + nt) * 64) + lane) * 8];
      acc[0][nt] = __builtin_amdgcn_mfma_f32_16x16x32_bf16(a0, b, acc[0][nt], 0, 0, 0);
      acc[1][nt] = __builtin_amdgcn_mfma_f32_16x16x32_bf16(a1, b, acc[1][nt], 0, 0, 0);
    }
  }

  // epilogue: + bias, NT store to out (bnc fp32). C/D: row=(lane>>4)*4+r, col=lane&15
  float bv[4];
#pragma unroll
  for (int nt = 0; nt < 4; ++nt) bv[nt] = bias[nt * 16 + (lane & 15)];
#pragma unroll
  for (int mt = 0; mt < 2; ++mt)
#pragma unroll
    for (int r = 0; r < 4; ++r) {
      int rl = mt * 16 + (lane >> 4) * 4 + r;
      int rn = row0 + rl;
      int b = rn & 7, nn = rn >> 3;
      float* orow = &out[((size_t)b * NN + nn) * 64 + (lane & 15)];
#pragma unroll
      for (int nt = 0; nt < 4; ++nt)
        __builtin_nontemporal_store(acc[mt][nt][r] + bv[nt], &orow[nt * 16]);
    }
}

// ---- fallback fp32 kernels (small-ws tiers) --------------------------------
__global__ __launch_bounds__(256) void cheb_prop(
    const float* __restrict__ tin, float* __restrict__ tout,
    const int* __restrict__ rowptr, const int* __restrict__ cnt,
    const int2* __restrict__ edges, int nwaves) {
  int wid = (blockIdx.x << 2) + (threadIdx.x >> 6);
  if (wid >= nwaves) return;
  int lane = threadIdx.x & 63;
  int b = wid / NN;
  int n = wid - b * NN;
  int s = rowptr[n];
  int e = s + cnt[n];
  const float* base = tin + (size_t)b * NN * NC;
  float acc = 0.0f;
  for (int j = s; j < e; ++j) {
    int2 ed = edges[j];
    acc += __int_as_float(ed.y) * base[(size_t)ed.x * NC + lane];
  }
  tout[((size_t)b * NN + n) * NC + lane] = acc;
}

__global__ __launch_bounds__(256) void cheb_gemm2(
    const float* __restrict__ x, const float* __restrict__ tx1,
    const float* ptx1, const float* __restrict__ wc,
    const float* __restrict__ bias, float* out, int nrows) {
  __shared__ float At[128][64];
  __shared__ float Ws[64][64];
  int tid = threadIdx.x;
  int tx = tid & 15;
  int ty = tid >> 4;
  long row0 = (long)blockIdx.x * 128;
  int sk4 = (tid & 15) * 4;
  int srb = tid >> 4;
  const float* sp[3] = {x, tx1, ptx1};
  float4 pa[8], pw[4];
  auto fetch = [&](int ch) {
    const float* s0 = sp[ch];
#pragma unroll
    for (int rr = 0; rr < 8; ++rr) {
      int roff = srb + rr * 16;
      if (row0 + roff < nrows)
        pa[rr] = *(const float4*)&s0[(size_t)(row0 + roff) * NC + sk4];
      else
        pa[rr] = make_float4(0.f, 0.f, 0.f, 0.f);
    }
#pragma unroll
    for (int ww = 0; ww < 4; ++ww) {
      int e4 = tid + 256 * ww;
      pw[ww] = *(const float4*)&wc[ch * 4096 + (e4 >> 4) * 64 + (e4 & 15) * 4];
    }
  };
  auto commit = [&]() {
#pragma unroll
    for (int rr = 0; rr < 8; ++rr)
      *(float4*)&At[srb + rr * 16][sk4] = pa[rr];
#pragma unroll
    for (int ww = 0; ww < 4; ++ww) {
      int e4 = tid + 256 * ww;
      *(float4*)&Ws[e4 >> 4][(e4 & 15) * 4] = pw[ww];
    }
  };
  float4 acc[8];
#pragma unroll
  for (int i = 0; i < 8; ++i) acc[i] = make_float4(0.f, 0.f, 0.f, 0.f);
  fetch(0);
  commit();
  for (int ch = 0; ch < 3; ++ch) {
    __syncthreads();
    if (ch < 2) fetch(ch + 1);
#pragma unroll 4
    for (int k4 = 0; k4 < 16; ++k4) {
      float4 w0 = *(float4*)&Ws[k4 * 4 + 0][tx * 4];
      float4 w1 = *(float4*)&Ws[k4 * 4 + 1][tx * 4];
      float4 w2 = *(float4*)&Ws[k4 * 4 + 2][tx * 4];
      float4 w3 = *(float4*)&Ws[k4 * 4 + 3][tx * 4];
#pragma unroll
      for (int i = 0; i < 8; ++i) {
        float4 a = *(float4*)&At[ty * 8 + i][k4 * 4];
        fma4(acc[i], a.x, w0);
        fma4(acc[i], a.y, w1);
        fma4(acc[i], a.z, w2);
        fma4(acc[i], a.w, w3);
      }
    }
    __syncthreads();
    if (ch < 2) commit();
  }
  float4 bb4 = *(const float4*)&bias[tx * 4];
#pragma unroll
  for (int i = 0; i < 8; ++i) {
    long r = row0 + ty * 8 + i;
    if (r >= nrows) continue;
    float4 o = make_float4(acc[i].x + bb4.x, acc[i].y + bb4.y,
                           acc[i].z + bb4.z, acc[i].w + bb4.w);
    *(float4*)&out[(size_t)r * NC + tx * 4] = o;
  }
}

extern "C" void kernel_launch(void* const* d_in, const int* in_sizes, int n_in,
                              void* d_out, int out_size, void* d_ws, size_t ws_size,
                              hipStream_t stream) {
  (void)in_sizes; (void)n_in; (void)out_size;
  const float* x    = (const float*)d_in[0];
  const float* w    = (const float*)d_in[1];
  const float* bias = (const float*)d_in[2];
  const int*   ei   = (const int*)d_in[3];
  float* out = (float*)d_out;
  char* ws = (char*)d_ws;

  size_t off = 0;
  auto alloc = [&](size_t bytes) -> void* {
    void* p = (void*)(ws + off);
    off = (off + bytes + 255) & ~(size_t)255;
    return p;
  };
  int* cnt      = (int*)alloc((size_t)(NN + 1) * sizeof(int));
  int* total    = cnt + NN;
  int* rowptr   = (int*)alloc((size_t)NN * sizeof(int));
  int* cur      = (int*)alloc((size_t)NN * sizeof(int));
  float* dinv   = (float*)alloc((size_t)NN * sizeof(float));
  int2* edges   = (int2*)alloc((size_t)NE * sizeof(int2));
  float* wcb    = (float*)alloc((size_t)3 * NC * NC * sizeof(float));
  unsigned short* pack = (unsigned short*)alloc((size_t)6 * 4 * 64 * 8 * sizeof(unsigned short));
  size_t small_end = off;

  hipMemsetAsync(cnt, 0, (NN + 1) * sizeof(int), stream);
  cheb_count  <<<(NE + 255) / 256, 256, 0, stream>>>(ei, cnt);
  cheb_offsets<<<(NN + 255) / 256, 256, 0, stream>>>(cnt, dinv, rowptr, cur, total);
  cheb_scatter<<<(NE + 255) / 256, 256, 0, stream>>>(ei, dinv, cur, edges);

  const size_t fieldHB = (size_t)NN * 512 * sizeof(unsigned short);  // 51.2 MB
  const size_t perbB   = (size_t)NN * NC * sizeof(float);            // 12.8 MB

  if (ws_size >= small_end + 2 * fieldHB + 256) {
    // Tier A: bf16 pipeline with fused prop2+MFMA GEMM
    unsigned short* xh   = (unsigned short*)alloc(fieldHB);
    unsigned short* tx1h = (unsigned short*)alloc(fieldHB);
    cheb_wpack  <<<(6 * 4 * 64 * 8 + 255) / 256, 256, 0, stream>>>(w, pack);
    cheb_convert<<<(NN * 128) / 256, 256, 0, stream>>>(x, xh);
    cheb_prop1h <<<NN / 4, 256, 0, stream>>>(xh, tx1h, rowptr, cnt, edges);
    cheb_fused  <<<(NB * NN) / 128, 256, 0, stream>>>(
        xh, tx1h, rowptr, cnt, edges, pack, bias, out);
  } else if (ws_size >= small_end + 2 * perbB + 256) {
    // Tier B: per-batch fp32 fallback
    cheb_wc<<<(NC * NC + 255) / 256, 256, 0, stream>>>(w, wcb);
    float* tx1b  = (float*)alloc(perbB);
    float* ptx1b = (float*)alloc(perbB);
    for (int b = 0; b < NB; ++b) {
      const float* xb = x + (size_t)b * NN * NC;
      float* outb = out + (size_t)b * NN * NC;
      cheb_prop<<<(NN + 3) / 4, 256, 0, stream>>>(xb, tx1b, rowptr, cnt, edges, NN);
      cheb_prop<<<(NN + 3) / 4, 256, 0, stream>>>(tx1b, ptx1b, rowptr, cnt, edges, NN);
      cheb_gemm2<<<(NN + 127) / 128, 256, 0, stream>>>(
          xb, tx1b, ptx1b, wcb, bias, outb, NN);
    }
  } else {
    // Tier C: per-batch fp32, ptx1 via out slice (gemm stages before writes)
    cheb_wc<<<(NC * NC + 255) / 256, 256, 0, stream>>>(w, wcb);
    float* tx1b = (float*)alloc(perbB);
    for (int b = 0; b < NB; ++b) {
      const float* xb = x + (size_t)b * NN * NC;
      float* outb = out + (size_t)b * NN * NC;
      cheb_prop<<<(NN + 3) / 4, 256, 0, stream>>>(xb, tx1b, rowptr, cnt, edges, NN);
      cheb_prop<<<(NN + 3) / 4, 256, 0, stream>>>(tx1b, outb, rowptr, cnt, edges, NN);
      cheb_gemm2<<<(NN + 127) / 128, 256, 0, stream>>>(
          xb, tx1b, outb, wcb, bias, outb, NN);
    }
  }
}